// Round 15
// baseline (791.603 us; speedup 1.0000x reference)
//
#include <hip/hip_runtime.h>
#include <hip/hip_bf16.h>

typedef __hip_bfloat16 bf16;
typedef unsigned short u16;
typedef unsigned char u8;

// bf16 bits -> f32 (exact)
static __device__ __forceinline__ float lo16(unsigned u) { return __uint_as_float(u << 16); }
static __device__ __forceinline__ float hi16(unsigned u) { return __uint_as_float(u & 0xFFFF0000u); }
// f32 -> bf16 bits, round-to-nearest-even (no NaNs in this pipeline)
static __device__ __forceinline__ unsigned f2u(float x) {
    unsigned u = __float_as_uint(x);
    return (u + 0x7FFFu + ((u >> 16) & 1u)) >> 16;
}
static __device__ __forceinline__ unsigned pack2(float a, float b) {
    return f2u(a) | (f2u(b) << 16);
}

// ---- problem constants ----
constexpr int D0 = 240, H0 = 144, W0 = 240;
constexpr int V  = D0 * H0 * W0;          // 8,294,400 voxels
constexpr int NPIX = 480 * 640;           // 307,200 pixels
constexpr int D1 = 120, H1 = 72, W1 = 120;
constexpr int N1 = D1 * H1 * W1;          // 1,036,800
constexpr int D2 = 60, H2 = 36, W2 = 60;
constexpr int N2 = D2 * H2 * W2;          // 129,600

// Volume layout: 3 groups x [V][4] bf16 (channel ci = 4*g + c)
constexpr size_t GRP_U16  = (size_t)V * 4;                    // u16 per group
constexpr size_t GRP_BYTES = GRP_U16 * sizeof(u16);           // 66,355,200
constexpr size_t SEG_BYTES = 3 * GRP_BYTES;                   // 199,065,600
constexpr size_t WIN_BYTES = (size_t)V * sizeof(unsigned);    // 33,177,600
constexpr int WCHUNKS  = (int)(WIN_BYTES / 16);               // 2,073,600 uint4
// Peak ws: SEG_BYTES + GRP_BYTES = 265,420,800 bytes — proven safe.
// (R14 established ws_size < 298.6 MB, so the 265.4 MB rotation is mandatory.)

// ============================================================
// Zero-fill (uint4) — now only the 33 MB winner array
// ============================================================
__global__ void __launch_bounds__(256) kz_zero16(uint4* __restrict__ p, int nchunks) {
    int i = blockIdx.x * 256 + threadIdx.x;
    if (i >= nchunks) return;
    p[i] = make_uint4(0u, 0u, 0u, 0u);
}

// ============================================================
// Scatter: last-write-wins via winner = max(pixel_index+1)
// ============================================================
__global__ void __launch_bounds__(256) kz_scatter_win(const int* __restrict__ depth,
                                                      unsigned* __restrict__ winner) {
    int p = blockIdx.x * 256 + threadIdx.x;
    if (p >= NPIX) return;
    int d = depth[p];
    if (d > 0 && d < V) atomicMax(&winner[d], (unsigned)(p + 1));
}

__global__ void __launch_bounds__(256) kz_scatter_write(const int* __restrict__ depth,
                                                        const unsigned* __restrict__ winner,
                                                        const float* __restrict__ feat,
                                                        u16* __restrict__ seg) {
    int p = blockIdx.x * 256 + threadIdx.x;
    if (p >= NPIX) return;
    int d = depth[p];
    if (d > 0 && d < V && winner[d] == (unsigned)(p + 1)) {
#pragma unroll
        for (int g = 0; g < 3; ++g) {
            uint2 val;
            val.x = pack2(feat[(4 * g + 0) * NPIX + p], feat[(4 * g + 1) * NPIX + p]);
            val.y = pack2(feat[(4 * g + 2) * NPIX + p], feat[(4 * g + 3) * NPIX + p]);
            *(uint2*)(seg + g * GRP_U16 + (size_t)d * 4) = val;
        }
    }
}

// ============================================================
// Gate build: gate[v] = (winner[v] != 0), one byte per voxel.
// 16 voxels/thread. winner dies after this kernel.
// ============================================================
__global__ void __launch_bounds__(256) kz_gate(const uint4* __restrict__ win,
                                               uint4* __restrict__ gate) {
    int i = blockIdx.x * 256 + threadIdx.x;   // grid exact: V/16/256 = 2025
    const uint4* wp = win + (size_t)i * 4;
    uint4 a = wp[0], b = wp[1], c = wp[2], d = wp[3];
    unsigned r0 = (a.x ? 1u : 0u) | (a.y ? 0x100u : 0u) | (a.z ? 0x10000u : 0u) | (a.w ? 0x1000000u : 0u);
    unsigned r1 = (b.x ? 1u : 0u) | (b.y ? 0x100u : 0u) | (b.z ? 0x10000u : 0u) | (b.w ? 0x1000000u : 0u);
    unsigned r2 = (c.x ? 1u : 0u) | (c.y ? 0x100u : 0u) | (c.z ? 0x10000u : 0u) | (c.w ? 0x1000000u : 0u);
    unsigned r3 = (d.x ? 1u : 0u) | (d.y ? 0x100u : 0u) | (d.z ? 0x10000u : 0u) | (d.w ? 0x1000000u : 0u);
    gate[i] = make_uint4(r0, r1, r2, r3);
}

// ============================================================
// One-pass LDS-shared avg-pool hole-fill (one group [V][4]).
// Raw loads gated by byte mask (volume NOT pre-zeroed).
// Block tile: 4d x 4h x 120w. Phase 1: 3-tap W row-sums for 36 halo rows
// into LDS. Phase 2: 9-row sum, /27, select vs raw, write out-of-place.
// ============================================================
constexpr int FTW = 120;
constexpr int FROWS = 36;

__global__ void __launch_bounds__(256) kz_fillL(const u16* __restrict__ rb,
                                                const u8* __restrict__ gate,
                                                u16* __restrict__ fb) {
    __shared__ u16 S[FROWS * FTW * 4];   // 34,560 B
    int bid = blockIdx.x;                 // grid: 60*36*2 = 4320
    int wt = bid & 1;
    int t1 = bid >> 1;
    int ht = t1 % 36;
    int dt = t1 / 36;
    int d0 = dt * 4, h0 = ht * 4, w0 = wt * 120;
    int tid = threadIdx.x;

    // Phase 1: 36 rows x 60 voxel-pair tasks
    for (int tt = tid; tt < FROWS * 60; tt += 256) {
        int hr = tt / 60;
        int pt = tt - hr * 60;
        int w = w0 + 2 * pt;
        int d = d0 - 1 + hr / 6;
        int h = h0 - 1 + hr % 6;
        uint4 O = make_uint4(0u, 0u, 0u, 0u);
        if (d >= 0 && d < D0 && h >= 0 && h < H0) {
            size_t row = (size_t)(d * H0 + h) * W0;
            size_t gi = row + w;
            const u16* rp = rb + gi * 4;
            uint4 X = *(const uint4*)(rp);
            if (gate[gi] == 0)     { X.x = 0u; X.y = 0u; }
            if (gate[gi + 1] == 0) { X.z = 0u; X.w = 0u; }
            float x0[4] = {lo16(X.x), hi16(X.x), lo16(X.y), hi16(X.y)};
            float x1[4] = {lo16(X.z), hi16(X.z), lo16(X.w), hi16(X.w)};
            float l[4] = {0.f, 0.f, 0.f, 0.f}, rr[4] = {0.f, 0.f, 0.f, 0.f};
            if (w > 0 && gate[gi - 1] != 0) {
                uint2 L = *(const uint2*)(rp - 4);
                l[0] = lo16(L.x); l[1] = hi16(L.x); l[2] = lo16(L.y); l[3] = hi16(L.y);
            }
            if (w < 238 && gate[gi + 2] != 0) {
                uint2 R = *(const uint2*)(rp + 8);
                rr[0] = lo16(R.x); rr[1] = hi16(R.x); rr[2] = lo16(R.y); rr[3] = hi16(R.y);
            }
            O.x = pack2(l[0] + x0[0] + x1[0], l[1] + x0[1] + x1[1]);
            O.y = pack2(l[2] + x0[2] + x1[2], l[3] + x0[3] + x1[3]);
            O.z = pack2(x0[0] + x1[0] + rr[0], x0[1] + x1[1] + rr[1]);
            O.w = pack2(x0[2] + x1[2] + rr[2], x0[3] + x1[3] + rr[3]);
        }
        *(uint4*)(S + ((size_t)hr * FTW + 2 * pt) * 4) = O;
    }
    __syncthreads();

    // Phase 2: 16 output rows x 60 voxel-pair tasks
    for (int ot = tid; ot < 16 * 60; ot += 256) {
        int orr = ot / 60;
        int pt = ot - orr * 60;
        int w = w0 + 2 * pt;
        int di = orr >> 2, hi_ = orr & 3;
        int d = d0 + di, h = h0 + hi_;
        float s[8] = {0.f, 0.f, 0.f, 0.f, 0.f, 0.f, 0.f, 0.f};
#pragma unroll
        for (int dd = 0; dd < 3; ++dd) {
#pragma unroll
            for (int dh = 0; dh < 3; ++dh) {
                int hr = (di + dd) * 6 + (hi_ + dh);
                uint4 T = *(const uint4*)(S + ((size_t)hr * FTW + 2 * pt) * 4);
                s[0] += lo16(T.x); s[1] += hi16(T.x); s[2] += lo16(T.y); s[3] += hi16(T.y);
                s[4] += lo16(T.z); s[5] += hi16(T.z); s[6] += lo16(T.w); s[7] += hi16(T.w);
            }
        }
        size_t row = (size_t)(d * H0 + h) * W0;
        size_t gi = row + w;
        uint4 Rv = *(const uint4*)(rb + gi * 4);
        if (gate[gi] == 0)     { Rv.x = 0u; Rv.y = 0u; }
        if (gate[gi + 1] == 0) { Rv.z = 0u; Rv.w = 0u; }
        constexpr float inv27 = 1.0f / 27.0f;
        uint4 Ov;
        Ov.x = ((Rv.x & 0x7FFFu) ? (Rv.x & 0xFFFFu) : f2u(s[0] * inv27))
             | ((((Rv.x >> 16) & 0x7FFFu) ? (Rv.x >> 16) : f2u(s[1] * inv27)) << 16);
        Ov.y = ((Rv.y & 0x7FFFu) ? (Rv.y & 0xFFFFu) : f2u(s[2] * inv27))
             | ((((Rv.y >> 16) & 0x7FFFu) ? (Rv.y >> 16) : f2u(s[3] * inv27)) << 16);
        Ov.z = ((Rv.z & 0x7FFFu) ? (Rv.z & 0xFFFFu) : f2u(s[4] * inv27))
             | ((((Rv.z >> 16) & 0x7FFFu) ? (Rv.z >> 16) : f2u(s[5] * inv27)) << 16);
        Ov.w = ((Rv.w & 0x7FFFu) ? (Rv.w & 0xFFFFu) : f2u(s[6] * inv27))
             | ((((Rv.w >> 16) & 0x7FFFu) ? (Rv.w >> 16) : f2u(s[7] * inv27)) << 16);
        *(uint4*)(fb + gi * 4) = Ov;
    }
}

// ============================================================
// Downsample 1 (R12/R13-proven body): conv 12->4 ++ maxpool2, relu
// -> x1 interleaved [N1][16]
// ============================================================
__global__ void __launch_bounds__(256) kz_ds1(const u16* __restrict__ f0g,
                                              const u16* __restrict__ f1g,
                                              const u16* __restrict__ f2g,
                                              const float* __restrict__ w,
                                              float* __restrict__ x1i) {
    __shared__ float wl[4 * 12 * 27];
    __shared__ float pool[12 * 256];
    for (int t = threadIdx.x; t < 4 * 12 * 27; t += 256) wl[t] = w[t];
    __syncthreads();
    int tid = threadIdx.x;
    int o = blockIdx.x * 256 + tid;    // grid exact: N1/256 = 4050
    int wo = o % W1;
    int t  = o / W1;
    int ho = t % H1;
    int d0 = t / H1;
    float acc[4] = {0.f, 0.f, 0.f, 0.f};
#pragma unroll 1
    for (int g = 0; g < 3; ++g) {
        const u16* base = (g == 0) ? f0g : ((g == 1) ? f1g : f2g);
        const float* wg = wl + (4 * g) * 27;
        float mx0 = -1e30f, mx1 = -1e30f, mx2 = -1e30f, mx3 = -1e30f;
#pragma unroll 1
        for (int kd = 0; kd < 3; ++kd) {
            int d2 = 2 * d0 - 1 + kd;
            bool dv = (d2 >= 0 && d2 < D0);
#pragma unroll
            for (int kh = 0; kh < 3; ++kh) {
                int h2 = 2 * ho - 1 + kh;
                bool rvv = dv && (h2 >= 0 && h2 < H0);
                float a0 = 0.f, a1 = 0.f, a2 = 0.f, a3 = 0.f;
                float b0 = 0.f, b1 = 0.f, b2 = 0.f, b3 = 0.f;
                float c0 = 0.f, c1 = 0.f, c2 = 0.f, c3 = 0.f;
                if (rvv) {
                    size_t r2 = (size_t)((d2 * H0 + h2) * W0 + 2 * wo);
                    uint4 AB = *(const uint4*)(base + r2 * 4);
                    b0 = lo16(AB.x); b1 = hi16(AB.x); b2 = lo16(AB.y); b3 = hi16(AB.y);
                    c0 = lo16(AB.z); c1 = hi16(AB.z); c2 = lo16(AB.w); c3 = hi16(AB.w);
                    if (wo > 0) {
                        uint2 P = *(const uint2*)(base + (r2 - 1) * 4);
                        a0 = lo16(P.x); a1 = hi16(P.x); a2 = lo16(P.y); a3 = hi16(P.y);
                    }
                }
                const float* wk = wg + kd * 9 + kh * 3;
#pragma unroll
                for (int m = 0; m < 4; ++m) {
                    const float* wm = wk + m * 324;
                    acc[m] += a0 * wm[0]  + b0 * wm[1]  + c0 * wm[2]
                            + a1 * wm[27] + b1 * wm[28] + c1 * wm[29]
                            + a2 * wm[54] + b2 * wm[55] + c2 * wm[56]
                            + a3 * wm[81] + b3 * wm[82] + c3 * wm[83];
                }
                if (kd >= 1 && kh >= 1) {
                    mx0 = fmaxf(mx0, fmaxf(b0, c0));
                    mx1 = fmaxf(mx1, fmaxf(b1, c1));
                    mx2 = fmaxf(mx2, fmaxf(b2, c2));
                    mx3 = fmaxf(mx3, fmaxf(b3, c3));
                }
            }
        }
        pool[(4 * g + 0) * 256 + tid] = fmaxf(mx0, 0.f);
        pool[(4 * g + 1) * 256 + tid] = fmaxf(mx1, 0.f);
        pool[(4 * g + 2) * 256 + tid] = fmaxf(mx2, 0.f);
        pool[(4 * g + 3) * 256 + tid] = fmaxf(mx3, 0.f);
    }
    float* xo = x1i + (size_t)o * 16;
    *(float4*)(xo)      = make_float4(fmaxf(acc[0], 0.f), fmaxf(acc[1], 0.f),
                                      fmaxf(acc[2], 0.f), fmaxf(acc[3], 0.f));
    *(float4*)(xo + 4)  = make_float4(pool[0 * 256 + tid], pool[1 * 256 + tid],
                                      pool[2 * 256 + tid], pool[3 * 256 + tid]);
    *(float4*)(xo + 8)  = make_float4(pool[4 * 256 + tid], pool[5 * 256 + tid],
                                      pool[6 * 256 + tid], pool[7 * 256 + tid]);
    *(float4*)(xo + 12) = make_float4(pool[8 * 256 + tid], pool[9 * 256 + tid],
                                      pool[10 * 256 + tid], pool[11 * 256 + tid]);
}

// ============================================================
// pw 16->4: x1 interleaved [N1][16] -> y0 interleaved [N1][4], relu
// ============================================================
__global__ void __launch_bounds__(256) kz_pw16to4i(const float* __restrict__ in,
                                                   const float* __restrict__ w,
                                                   float* __restrict__ out) {
    __shared__ float wl[64];
    if (threadIdx.x < 64) wl[threadIdx.x] = w[threadIdx.x];
    __syncthreads();
    int o = blockIdx.x * 256 + threadIdx.x;   // exact
    const float* ip = in + (size_t)o * 16;
    float4 A = *(const float4*)(ip);
    float4 B = *(const float4*)(ip + 4);
    float4 C = *(const float4*)(ip + 8);
    float4 D = *(const float4*)(ip + 12);
    float r[4];
#pragma unroll
    for (int m = 0; m < 4; ++m) {
        const float* wm = wl + m * 16;
        r[m] = A.x * wm[0] + A.y * wm[1] + A.z * wm[2] + A.w * wm[3]
             + B.x * wm[4] + B.y * wm[5] + B.z * wm[6] + B.w * wm[7]
             + C.x * wm[8] + C.y * wm[9] + C.z * wm[10] + C.w * wm[11]
             + D.x * wm[12] + D.y * wm[13] + D.z * wm[14] + D.w * wm[15];
    }
    *(float4*)(out + (size_t)o * 4) = make_float4(fmaxf(r[0], 0.f), fmaxf(r[1], 0.f),
                                                  fmaxf(r[2], 0.f), fmaxf(r[3], 0.f));
}

// ============================================================
// bconv 4ch interleaved [N1][4]: (KD,KH,KW), bias, NADD residuals, relu
// ============================================================
template <int KD, int KH, int KW, int NADD>
__global__ void __launch_bounds__(256) kz_bconv4i(const float* __restrict__ in,
                                                  const float* __restrict__ w,
                                                  const float* __restrict__ b,
                                                  const float* __restrict__ add1,
                                                  const float* __restrict__ add2,
                                                  float* __restrict__ out) {
    constexpr int S = KD * KH * KW;
    __shared__ float wl[16 * S];
    __shared__ float bl[4];
    for (int t = threadIdx.x; t < 16 * S; t += 256) wl[t] = w[t];
    if (threadIdx.x < 4) bl[threadIdx.x] = b[threadIdx.x];
    __syncthreads();
    int o = blockIdx.x * 256 + threadIdx.x;   // exact: N1/256
    int wo = o % W1;
    int t  = o / W1;
    int ho = t % H1;
    int d0 = t / H1;
    float a0 = bl[0], a1 = bl[1], a2 = bl[2], a3 = bl[3];
#pragma unroll
    for (int kd = 0; kd < KD; ++kd) {
        int d2 = d0 + kd - KD / 2;
        if (KD > 1 && (d2 < 0 || d2 >= D1)) continue;
#pragma unroll
        for (int kh = 0; kh < KH; ++kh) {
            int h2 = ho + kh - KH / 2;
            if (KH > 1 && (h2 < 0 || h2 >= H1)) continue;
#pragma unroll
            for (int kw = 0; kw < KW; ++kw) {
                int w2 = wo + kw - KW / 2;
                if (KW > 1 && (w2 < 0 || w2 >= W1)) continue;
                float4 v = *(const float4*)(in + (size_t)((d2 * H1 + h2) * W1 + w2) * 4);
                int tap = (kd * KH + kh) * KW + kw;
                const float* wt = wl + tap;
                a0 += v.x * wt[0 * S] + v.y * wt[1 * S] + v.z * wt[2 * S] + v.w * wt[3 * S];
                a1 += v.x * wt[4 * S] + v.y * wt[5 * S] + v.z * wt[6 * S] + v.w * wt[7 * S];
                a2 += v.x * wt[8 * S] + v.y * wt[9 * S] + v.z * wt[10 * S] + v.w * wt[11 * S];
                a3 += v.x * wt[12 * S] + v.y * wt[13 * S] + v.z * wt[14 * S] + v.w * wt[15 * S];
            }
        }
    }
    if (NADD >= 1) {
        float4 r1 = *(const float4*)(add1 + (size_t)o * 4);
        a0 += r1.x; a1 += r1.y; a2 += r1.z; a3 += r1.w;
    }
    if (NADD >= 2) {
        float4 r2 = *(const float4*)(add2 + (size_t)o * 4);
        a0 += r2.x; a1 += r2.y; a2 += r2.z; a3 += r2.w;
    }
    *(float4*)(out + (size_t)o * 4) = make_float4(fmaxf(a0, 0.f), fmaxf(a1, 0.f),
                                                  fmaxf(a2, 0.f), fmaxf(a3, 0.f));
}

// ============================================================
// FUSED: bconv4 (3,1,3) + bias + 2 residuals + relu -> pw 4->16
//        + residual(x1i) + relu -> x1b PLANAR [16][N1]
// ============================================================
__global__ void __launch_bounds__(256) kz_bconv4i_pw(const float* __restrict__ in,
                                                     const float* __restrict__ w,
                                                     const float* __restrict__ b,
                                                     const float* __restrict__ add1,
                                                     const float* __restrict__ add2,
                                                     const float* __restrict__ wp,
                                                     const float* __restrict__ x1i,
                                                     float* __restrict__ out) {
    constexpr int S = 9;   // 3*1*3
    __shared__ float wl[16 * S];
    __shared__ float bl[4];
    __shared__ float wpl[64];
    for (int t = threadIdx.x; t < 16 * S; t += 256) wl[t] = w[t];
    if (threadIdx.x < 4) bl[threadIdx.x] = b[threadIdx.x];
    if (threadIdx.x < 64) wpl[threadIdx.x] = wp[threadIdx.x];
    __syncthreads();
    int o = blockIdx.x * 256 + threadIdx.x;   // exact
    int wo = o % W1;
    int t  = o / W1;
    int ho = t % H1;
    int d0 = t / H1;
    float a0 = bl[0], a1 = bl[1], a2 = bl[2], a3 = bl[3];
#pragma unroll
    for (int kd = 0; kd < 3; ++kd) {
        int d2 = d0 + kd - 1;
        if (d2 < 0 || d2 >= D1) continue;
#pragma unroll
        for (int kw = 0; kw < 3; ++kw) {
            int w2 = wo + kw - 1;
            if (w2 < 0 || w2 >= W1) continue;
            float4 v = *(const float4*)(in + (size_t)((d2 * H1 + ho) * W1 + w2) * 4);
            int tap = kd * 3 + kw;
            const float* wt = wl + tap;
            a0 += v.x * wt[0 * S] + v.y * wt[1 * S] + v.z * wt[2 * S] + v.w * wt[3 * S];
            a1 += v.x * wt[4 * S] + v.y * wt[5 * S] + v.z * wt[6 * S] + v.w * wt[7 * S];
            a2 += v.x * wt[8 * S] + v.y * wt[9 * S] + v.z * wt[10 * S] + v.w * wt[11 * S];
            a3 += v.x * wt[12 * S] + v.y * wt[13 * S] + v.z * wt[14 * S] + v.w * wt[15 * S];
        }
    }
    float4 r1 = *(const float4*)(add1 + (size_t)o * 4);
    float4 r2 = *(const float4*)(add2 + (size_t)o * 4);
    float y0 = fmaxf(a0 + r1.x + r2.x, 0.f);
    float y1 = fmaxf(a1 + r1.y + r2.y, 0.f);
    float y2 = fmaxf(a2 + r1.z + r2.z, 0.f);
    float y3 = fmaxf(a3 + r1.w + r2.w, 0.f);
    const float* rp = x1i + (size_t)o * 16;
    float4 R0 = *(const float4*)(rp);
    float4 R1 = *(const float4*)(rp + 4);
    float4 R2 = *(const float4*)(rp + 8);
    float4 R3 = *(const float4*)(rp + 12);
    float rr[16] = {R0.x, R0.y, R0.z, R0.w, R1.x, R1.y, R1.z, R1.w,
                    R2.x, R2.y, R2.z, R2.w, R3.x, R3.y, R3.z, R3.w};
#pragma unroll
    for (int m = 0; m < 16; ++m) {
        const float* wm = wpl + m * 4;
        float r = y0 * wm[0] + y1 * wm[1] + y2 * wm[2] + y3 * wm[3] + rr[m];
        out[(size_t)m * N1 + o] = fmaxf(r, 0.f);
    }
}

// ============================================================
// FUSED Downsample 2 + pw 32->8 (R12-proven)
// ============================================================
__global__ void __launch_bounds__(256) kz_ds2f(const float* __restrict__ in,
                                               const float* __restrict__ w,
                                               const float* __restrict__ wz,
                                               float* __restrict__ out,
                                               float* __restrict__ z0i) {
    __shared__ float wl[16 * 16 * 27];
    __shared__ float wzl[256];
    for (int t = threadIdx.x; t < 16 * 16 * 27; t += 256) wl[t] = w[t];
    if (threadIdx.x < 256) wzl[threadIdx.x] = wz[threadIdx.x];
    __syncthreads();
    int o = blockIdx.x * 256 + threadIdx.x;
    if (o >= N2) return;
    int wo = o % W2;
    int t  = o / W2;
    int ho = t % H2;
    int d0 = t / H2;
    float acc[16];
    float zacc[8];
#pragma unroll
    for (int m = 0; m < 16; ++m) acc[m] = 0.f;
#pragma unroll
    for (int m = 0; m < 8; ++m) zacc[m] = 0.f;
#pragma unroll 1
    for (int ci = 0; ci < 16; ++ci) {
        const float* base = in + ci * N1;
        const float* wci = wl + ci * 27;
        float mx = -1e30f;
#pragma unroll 1
        for (int kd = 0; kd < 3; ++kd) {
            int d2 = 2 * d0 - 1 + kd;
            bool dv = (d2 >= 0 && d2 < D1);
#pragma unroll
            for (int kh = 0; kh < 3; ++kh) {
                int h2 = 2 * ho - 1 + kh;
                bool rvv = dv && (h2 >= 0 && h2 < H1);
                float vm1 = 0.f, v0 = 0.f, v1 = 0.f;
                if (rvv) {
                    int r2 = (d2 * H1 + h2) * W1 + 2 * wo;
                    float2 pb = *(const float2*)(base + r2);
                    v0 = pb.x; v1 = pb.y;
                    if (wo > 0) {
                        float2 pa = *(const float2*)(base + r2 - 2);
                        vm1 = pa.y;
                    }
                }
                const float* wk = wci + kd * 9 + kh * 3;
#pragma unroll
                for (int m = 0; m < 16; ++m)
                    acc[m] += vm1 * wk[m * 432] + v0 * wk[m * 432 + 1] + v1 * wk[m * 432 + 2];
                if (kd >= 1 && kh >= 1) mx = fmaxf(mx, fmaxf(v0, v1));
            }
        }
        float pl = fmaxf(mx, 0.f);
        out[(16 + ci) * N2 + o] = pl;
#pragma unroll
        for (int m = 0; m < 8; ++m) zacc[m] += wzl[m * 32 + 16 + ci] * pl;
    }
#pragma unroll
    for (int j = 0; j < 16; ++j) {
        float cj = fmaxf(acc[j], 0.f);
        out[j * N2 + o] = cj;
#pragma unroll
        for (int m = 0; m < 8; ++m) zacc[m] += wzl[m * 32 + j] * cj;
    }
    float* op = z0i + (size_t)o * 8;
    *(float4*)(op)     = make_float4(fmaxf(zacc[0], 0.f), fmaxf(zacc[1], 0.f),
                                     fmaxf(zacc[2], 0.f), fmaxf(zacc[3], 0.f));
    *(float4*)(op + 4) = make_float4(fmaxf(zacc[4], 0.f), fmaxf(zacc[5], 0.f),
                                     fmaxf(zacc[6], 0.f), fmaxf(zacc[7], 0.f));
}

// ============================================================
// bconv 8ch interleaved [N2][8] (R12-proven)
// ============================================================
template <int KD, int KH, int KW, int NADD>
__global__ void __launch_bounds__(256) kz_bconv8i(const float* __restrict__ in,
                                                  const float* __restrict__ w,
                                                  const float* __restrict__ b,
                                                  const float* __restrict__ add1,
                                                  const float* __restrict__ add2,
                                                  float* __restrict__ out) {
    constexpr int S = KD * KH * KW;
    __shared__ float wl[64 * S];
    __shared__ float bl[8];
    for (int t = threadIdx.x; t < 64 * S; t += 256) wl[t] = w[t];
    if (threadIdx.x < 8) bl[threadIdx.x] = b[threadIdx.x];
    __syncthreads();
    int o = blockIdx.x * 256 + threadIdx.x;
    if (o >= N2) return;
    int wo = o % W2;
    int t  = o / W2;
    int ho = t % H2;
    int d0 = t / H2;
    float acc[8];
#pragma unroll
    for (int m = 0; m < 8; ++m) acc[m] = bl[m];
#pragma unroll
    for (int kd = 0; kd < KD; ++kd) {
        int d2 = d0 + kd - KD / 2;
        if (KD > 1 && (d2 < 0 || d2 >= D2)) continue;
#pragma unroll
        for (int kh = 0; kh < KH; ++kh) {
            int h2 = ho + kh - KH / 2;
            if (KH > 1 && (h2 < 0 || h2 >= H2)) continue;
#pragma unroll
            for (int kw = 0; kw < KW; ++kw) {
                int w2 = wo + kw - KW / 2;
                if (KW > 1 && (w2 < 0 || w2 >= W2)) continue;
                const float* vp = in + (size_t)((d2 * H2 + h2) * W2 + w2) * 8;
                float4 v0 = *(const float4*)(vp);
                float4 v1 = *(const float4*)(vp + 4);
                int tap = (kd * KH + kh) * KW + kw;
                const float* wt = wl + tap;
#pragma unroll
                for (int m = 0; m < 8; ++m) {
                    const float* wm = wt + m * 8 * S;
                    acc[m] += v0.x * wm[0] + v0.y * wm[S] + v0.z * wm[2 * S] + v0.w * wm[3 * S]
                            + v1.x * wm[4 * S] + v1.y * wm[5 * S] + v1.z * wm[6 * S] + v1.w * wm[7 * S];
                }
            }
        }
    }
    if (NADD >= 1) {
        const float* ap = add1 + (size_t)o * 8;
        float4 r0 = *(const float4*)(ap), r1 = *(const float4*)(ap + 4);
        acc[0] += r0.x; acc[1] += r0.y; acc[2] += r0.z; acc[3] += r0.w;
        acc[4] += r1.x; acc[5] += r1.y; acc[6] += r1.z; acc[7] += r1.w;
    }
    if (NADD >= 2) {
        const float* ap = add2 + (size_t)o * 8;
        float4 r0 = *(const float4*)(ap), r1 = *(const float4*)(ap + 4);
        acc[0] += r0.x; acc[1] += r0.y; acc[2] += r0.z; acc[3] += r0.w;
        acc[4] += r1.x; acc[5] += r1.y; acc[6] += r1.z; acc[7] += r1.w;
    }
    float* op = out + (size_t)o * 8;
    *(float4*)(op)     = make_float4(fmaxf(acc[0], 0.f), fmaxf(acc[1], 0.f),
                                     fmaxf(acc[2], 0.f), fmaxf(acc[3], 0.f));
    *(float4*)(op + 4) = make_float4(fmaxf(acc[4], 0.f), fmaxf(acc[5], 0.f),
                                     fmaxf(acc[6], 0.f), fmaxf(acc[7], 0.f));
}

// ============================================================
// FUSED: bconv8 (3,1,3) + residuals + relu -> pw 8->32 + residual + relu
// -> d_out planar [32][N2] (R12-proven)
// ============================================================
__global__ void __launch_bounds__(256) kz_bconv8i_pw(const float* __restrict__ in,
                                                     const float* __restrict__ w,
                                                     const float* __restrict__ b,
                                                     const float* __restrict__ add1,
                                                     const float* __restrict__ add2,
                                                     const float* __restrict__ wp,
                                                     const float* __restrict__ resp,
                                                     float* __restrict__ out) {
    constexpr int S = 9;   // 3*1*3
    __shared__ float wl[64 * S];
    __shared__ float bl[8];
    __shared__ float wpl[256];
    for (int t = threadIdx.x; t < 64 * S; t += 256) wl[t] = w[t];
    if (threadIdx.x < 8) bl[threadIdx.x] = b[threadIdx.x];
    if (threadIdx.x < 256) wpl[threadIdx.x] = wp[threadIdx.x];
    __syncthreads();
    int o = blockIdx.x * 256 + threadIdx.x;
    if (o >= N2) return;
    int wo = o % W2;
    int t  = o / W2;
    int ho = t % H2;
    int d0 = t / H2;
    float acc[8];
#pragma unroll
    for (int m = 0; m < 8; ++m) acc[m] = bl[m];
#pragma unroll
    for (int kd = 0; kd < 3; ++kd) {
        int d2 = d0 + kd - 1;
        if (d2 < 0 || d2 >= D2) continue;
#pragma unroll
        for (int kw = 0; kw < 3; ++kw) {
            int w2 = wo + kw - 1;
            if (w2 < 0 || w2 >= W2) continue;
            const float* vp = in + (size_t)((d2 * H2 + ho) * W2 + w2) * 8;
            float4 v0 = *(const float4*)(vp);
            float4 v1 = *(const float4*)(vp + 4);
            int tap = kd * 3 + kw;
            const float* wt = wl + tap;
#pragma unroll
            for (int m = 0; m < 8; ++m) {
                const float* wm = wt + m * 8 * S;
                acc[m] += v0.x * wm[0] + v0.y * wm[S] + v0.z * wm[2 * S] + v0.w * wm[3 * S]
                        + v1.x * wm[4 * S] + v1.y * wm[5 * S] + v1.z * wm[6 * S] + v1.w * wm[7 * S];
            }
        }
    }
    {
        const float* ap = add1 + (size_t)o * 8;
        float4 r0 = *(const float4*)(ap), r1 = *(const float4*)(ap + 4);
        acc[0] += r0.x; acc[1] += r0.y; acc[2] += r0.z; acc[3] += r0.w;
        acc[4] += r1.x; acc[5] += r1.y; acc[6] += r1.z; acc[7] += r1.w;
    }
    {
        const float* ap = add2 + (size_t)o * 8;
        float4 r0 = *(const float4*)(ap), r1 = *(const float4*)(ap + 4);
        acc[0] += r0.x; acc[1] += r0.y; acc[2] += r0.z; acc[3] += r0.w;
        acc[4] += r1.x; acc[5] += r1.y; acc[6] += r1.z; acc[7] += r1.w;
    }
#pragma unroll
    for (int m = 0; m < 8; ++m) acc[m] = fmaxf(acc[m], 0.f);
#pragma unroll
    for (int m = 0; m < 32; ++m) {
        const float* wm = wpl + m * 8;
        float r = acc[0] * wm[0] + acc[1] * wm[1] + acc[2] * wm[2] + acc[3] * wm[3]
                + acc[4] * wm[4] + acc[5] * wm[5] + acc[6] * wm[6] + acc[7] * wm[7];
        r += resp[(size_t)m * N2 + o];
        out[(size_t)m * N2 + o] = fmaxf(r, 0.f);
    }
}

// ============================================================
extern "C" void kernel_launch(void* const* d_in, const int* in_sizes, int n_in,
                              void* d_out, int out_size, void* d_ws, size_t ws_size,
                              hipStream_t stream) {
    const float* feat   = (const float*)d_in[0];
    const int*   depth  = (const int*)d_in[1];
    const float* w_ds1  = (const float*)d_in[2];
    const float* b1_win = (const float*)d_in[3];
    const float* b1w133 = (const float*)d_in[4];
    const float* b1b133 = (const float*)d_in[5];
    const float* b1w331 = (const float*)d_in[6];
    const float* b1b331 = (const float*)d_in[7];
    const float* b1w313 = (const float*)d_in[8];
    const float* b1b313 = (const float*)d_in[9];
    const float* b1wout = (const float*)d_in[10];
    const float* w_ds2  = (const float*)d_in[11];
    const float* b2_win = (const float*)d_in[12];
    const float* b2w133 = (const float*)d_in[13];
    const float* b2b133 = (const float*)d_in[14];
    const float* b2w331 = (const float*)d_in[15];
    const float* b2b331 = (const float*)d_in[16];
    const float* b2w313 = (const float*)d_in[17];
    const float* b2b313 = (const float*)d_in[18];
    const float* b2wout = (const float*)d_in[19];

    char* base = (char*)d_ws;

    // --- Region layout (time-shared; peak = 265.4 MB, proven safe) ---
    u16* raw0 = (u16*)base;                               // [0, 66.35)
    u16* raw1 = (u16*)(base + GRP_BYTES);                 // [66.35, 132.7)
    u16* raw2 = (u16*)(base + 2 * GRP_BYTES);             // [132.7, 199.07)
    unsigned* winner = (unsigned*)(base + SEG_BYTES);     // [199.07, 232.25); dead after kz_gate
    u16* fil0 = (u16*)(base + SEG_BYTES);                 // [199.07, 265.4) (winner dead)
    u16* fil1 = (u16*)base;                               // [0, 66.35)   after raw0 dies
    u16* fil2 = (u16*)(base + GRP_BYTES);                 // [66.35,132.7) after raw1 dies
    float* x1i = (float*)(base + 2 * GRP_BYTES);          // [132.7,199.07) after raw2 dies
    float* y0i = (float*)base;                            // after fil1/fil2 die (post-ds1)
    float* y1i = y0i + 4 * N1;
    float* y2i = y1i + 4 * N1;
    float* x1b = (float*)(base + SEG_BYTES);              // [199.07,265.4) (fil0 dead)
    float* x2  = (float*)base;                            // after y dead
    float* z0i = x2 + 32 * N2;
    float* z1i = z0i + 8 * N2;
    float* z2i = z1i + 8 * N2;

    float* out = (float*)d_out;   // reference output dtype is float32
    // Gate scratch: first 8.3 MB of d_out (byte per voxel); fully overwritten
    // by the final kernel.
    u8* gate = (u8*)d_out;

    // 1. zero ONLY the winner array (raw volume is never pre-zeroed;
    //    fill reads are gate-masked)
    kz_zero16<<<WCHUNKS / 256, 256, 0, stream>>>((uint4*)winner, WCHUNKS);

    // 2. deterministic last-write-wins scatter
    kz_scatter_win  <<<NPIX / 256, 256, 0, stream>>>(depth, winner);
    kz_scatter_write<<<NPIX / 256, 256, 0, stream>>>(depth, winner, feat, raw0);

    // 3. gate = (winner != 0) as bytes into d_out scratch; winner dies here
    kz_gate<<<(V / 16) / 256, 256, 0, stream>>>((const uint4*)winner, (uint4*)gate);

    // 4. one-pass LDS-shared hole-fill, gate-masked, out-of-place (rotating)
    kz_fillL<<<4320, 256, 0, stream>>>(raw0, gate, fil0);
    kz_fillL<<<4320, 256, 0, stream>>>(raw1, gate, fil1);
    kz_fillL<<<4320, 256, 0, stream>>>(raw2, gate, fil2);

    // 5. downsample 1 -> x1 interleaved [N1][16]
    kz_ds1<<<N1 / 256, 256, 0, stream>>>(fil0, fil1, fil2, w_ds1, x1i);

    // 6. bottleneck 1 (interleaved [N1][4]); last bconv fused with pw4->16
    kz_pw16to4i<<<N1 / 256, 256, 0, stream>>>(x1i, b1_win, y0i);
    kz_bconv4i<1, 3, 3, 0><<<N1 / 256, 256, 0, stream>>>(y0i, b1w133, b1b133, nullptr, nullptr, y1i);
    kz_bconv4i<3, 3, 1, 1><<<N1 / 256, 256, 0, stream>>>(y1i, b1w331, b1b331, y1i, nullptr, y2i);
    kz_bconv4i_pw<<<N1 / 256, 256, 0, stream>>>(y2i, b1w313, b1b313, y2i, y1i, b1wout, x1i, x1b);

    // 7. downsample 2 fused with pw32->8 -> x2 planar + z0 interleaved
    kz_ds2f<<<(N2 + 255) / 256, 256, 0, stream>>>(x1b, w_ds2, b2_win, x2, z0i);

    // 8. bottleneck 2 (interleaved [N2][8]); last bconv fused with pw8->32
    kz_bconv8i<1, 3, 3, 0><<<(N2 + 255) / 256, 256, 0, stream>>>(z0i, b2w133, b2b133, nullptr, nullptr, z1i);
    kz_bconv8i<3, 3, 1, 1><<<(N2 + 255) / 256, 256, 0, stream>>>(z1i, b2w331, b2b331, z1i, nullptr, z2i);
    kz_bconv8i_pw<<<(N2 + 255) / 256, 256, 0, stream>>>(z2i, b2w313, b2b313, z2i, z1i, b2wout, x2, out);

    (void)in_sizes; (void)n_in; (void)out_size; (void)ws_size;
}